// Round 6
// baseline (286.562 us; speedup 1.0000x reference)
//
#include <hip/hip_runtime.h>
#include <hip/hip_bf16.h>

// NeuroselectiveLinear: y = gather(x, in_idx) @ W^T + b, scattered into a
// zeroed [B,S,4096] buffer.
// Pipeline: memset(pos) -> prep (bf16 W row-major + inverse pos map) ->
// gather (coalesced x -> compact bf16 Xa) -> gemmfw (128x128 MFMA tiles,
// m97-structure; epilogue writes each tile's DENSE out-column range
// [out_idx[128*nb], out_idx[128*(nb+1)]) with zeros merged -- sorted out_idx
// makes ranges contiguous, disjoint, and complete. No expand kernel.)

typedef unsigned short u16;
typedef u16   u16x4 __attribute__((ext_vector_type(4)));
typedef int   i32x4 __attribute__((ext_vector_type(4)));
typedef float f32x4 __attribute__((ext_vector_type(4)));
typedef __bf16 bf16x8 __attribute__((ext_vector_type(8)));

constexpr int IN_F  = 4096;
constexpr int OUT_F = 4096;
constexpr int AI    = 1024;      // ACTIVE_IN  (K)
constexpr int AO    = 1024;      // ACTIVE_OUT (N)
constexpr int M_ROWS = 4 * 2048; // 8192

__device__ __forceinline__ u16 f2bf(float f) {
    union { __hip_bfloat16 h; u16 u; } cv;
    cv.h = __float2bfloat16(f);   // RNE
    return cv.u;
}
__device__ __forceinline__ float bf2f(u16 u) {
    union { float f; unsigned int i; } cv;
    cv.i = ((unsigned int)u) << 16;
    return cv.f;
}

// Wb = bf16(W) row-major [AO][AI]; pos[out_idx[j]] = j (pos pre-memset -1).
__global__ void prep_kernel(const float* __restrict__ W,
                            const int* __restrict__ out_idx,
                            u16* __restrict__ Wb, int* __restrict__ pos) {
    int t = blockIdx.x * blockDim.x + threadIdx.x; // 0..262143
    if (t < AO) pos[out_idx[t]] = t;
    f32x4 w = reinterpret_cast<const f32x4*>(W)[t];
    u16x4 v;
    v.x = f2bf(w.x); v.y = f2bf(w.y); v.z = f2bf(w.z); v.w = f2bf(w.w);
    reinterpret_cast<u16x4*>(Wb)[t] = v;
}

// One block per row: coalesced dense row load -> LDS, then LDS gather.
__global__ __launch_bounds__(256)
void gather_kernel(const float* __restrict__ x,
                   const int* __restrict__ in_idx,
                   u16* __restrict__ Xa) {
    __shared__ float xrow[IN_F];
    const int m = blockIdx.x;
    const int t = threadIdx.x;
    const f32x4* src = reinterpret_cast<const f32x4*>(x + (size_t)m * IN_F);
#pragma unroll
    for (int i = 0; i < 4; ++i)
        *reinterpret_cast<f32x4*>(&xrow[i * 1024 + t * 4]) = src[i * 256 + t];
    __syncthreads();
    i32x4 idx = reinterpret_cast<const i32x4*>(in_idx)[t];
    u16x4 v;
    v.x = f2bf(xrow[idx.x]);
    v.y = f2bf(xrow[idx.y]);
    v.z = f2bf(xrow[idx.z]);
    v.w = f2bf(xrow[idx.w]);
    reinterpret_cast<u16x4*>(Xa + (size_t)m * AI)[t] = v;
}

// 128x128 tile, BK=64, 4 waves (2x2), 4x4 16x16x32 frags/wave, dbuf LDS via
// global_load_lds w=16. Epilogue: park y(+bias) bf16 in LDS (aliasing the
// dead A/B tiles), then write this tile's dense out-column range.
__global__ __launch_bounds__(256, 2)
void gemmfw_kernel(const u16* __restrict__ Xa, const u16* __restrict__ Wb,
                   const float* __restrict__ bias,
                   const int* __restrict__ out_idx,
                   const int* __restrict__ pos, float* __restrict__ out) {
    __shared__ u16 S[4][128 * 64];   // As[0],As[1],Bs[0],Bs[1]; ys aliases S
    const int t    = threadIdx.x;
    const int wid  = t >> 6;
    const int lane = t & 63;
    const int n_lo = lane & 15;
    const int kg   = lane >> 4;
    // XCD swizzle: 512 blocks; each XCD gets 8 mb-groups x all 8 nb ->
    // its Xa panels (2MB) + full Wb (2MB) fit the 4MB per-XCD L2.
    const int orig = blockIdx.x;
    const int wgid = (orig & 7) * 64 + (orig >> 3);
    const int mb = wgid >> 3, nb = wgid & 7;
    const int m0 = mb * 128, n0 = nb * 128;
    const int wm = wid >> 1, wn = wid & 1;

    const int r8 = lane >> 3;
    const int c8 = (lane & 7) * 8;
    auto stage = [&](int buf, int k0) {
#pragma unroll
        for (int c = 0; c < 4; ++c) {
            const int row = wid * 32 + c * 8;
            __builtin_amdgcn_global_load_lds(
                (const __attribute__((address_space(1))) void*)
                    (Xa + (size_t)(m0 + row + r8) * AI + k0 + c8),
                (__attribute__((address_space(3))) void*)&S[buf][row * 64],
                16, 0, 0);
            __builtin_amdgcn_global_load_lds(
                (const __attribute__((address_space(1))) void*)
                    (Wb + (size_t)(n0 + row + r8) * AI + k0 + c8),
                (__attribute__((address_space(3))) void*)&S[2 + buf][row * 64],
                16, 0, 0);
        }
    };

    f32x4 acc[4][4];
#pragma unroll
    for (int i = 0; i < 4; ++i)
#pragma unroll
        for (int j = 0; j < 4; ++j) acc[i][j] = (f32x4)0.0f;

    stage(0, 0);
    int buf = 0;
    for (int kt = 0; kt < AI / 64; ++kt) {
        __syncthreads();
        if (kt + 1 < AI / 64) stage(buf ^ 1, (kt + 1) * 64);
#pragma unroll
        for (int kk = 0; kk < 64; kk += 32) {
            bf16x8 a[4], b[4];
#pragma unroll
            for (int i = 0; i < 4; ++i)
                a[i] = *reinterpret_cast<const bf16x8*>(
                    &S[buf][(wm * 64 + i * 16 + n_lo) * 64 + kk + kg * 8]);
#pragma unroll
            for (int j = 0; j < 4; ++j)
                b[j] = *reinterpret_cast<const bf16x8*>(
                    &S[2 + buf][(wn * 64 + j * 16 + n_lo) * 64 + kk + kg * 8]);
#pragma unroll
            for (int i = 0; i < 4; ++i)
#pragma unroll
                for (int j = 0; j < 4; ++j)
                    acc[i][j] = __builtin_amdgcn_mfma_f32_16x16x32_bf16(
                        a[i], b[j], acc[i][j], 0, 0, 0);
        }
        buf ^= 1;
    }

    float bv[4];
#pragma unroll
    for (int j = 0; j < 4; ++j) bv[j] = bias[n0 + wn * 64 + j * 16 + n_lo];

    __syncthreads();  // all waves done with A/B tiles before aliasing as ys
    u16* ys = &S[0][0];               // [128][136] bf16 (34.8 KB < 64 KB)
#pragma unroll
    for (int i = 0; i < 4; ++i)
#pragma unroll
        for (int j = 0; j < 4; ++j)
#pragma unroll
            for (int r = 0; r < 4; ++r)
                ys[(wm * 64 + i * 16 + kg * 4 + r) * 136 +
                   wn * 64 + j * 16 + n_lo] = f2bf(acc[i][j][r] + bv[j]);
    __syncthreads();

    // Dense write of this tile's out-column range (sorted out_idx =>
    // contiguous, disjoint, complete partition of [0,4096)).
    const int lo = (nb == 0) ? 0 : out_idx[nb * 128];
    const int hi = (nb == 7) ? OUT_F : out_idx[(nb + 1) * 128];
    const int s4 = (lo + 3) >> 2;     // first full f32x4
    const int e4 = hi >> 2;           // one past last full f32x4
    const i32x4* pos4 = reinterpret_cast<const i32x4*>(pos);
    const int rg = t >> 5, j32 = t & 31;  // 32 threads per row, 8 rows/iter
#pragma unroll 1
    for (int rr = 0; rr < 128; rr += 8) {
        const int row = rr + rg;
        float* orow = out + (size_t)(m0 + row) * OUT_F;
        const u16* yr = ys + row * 136;
        for (int c = lo + j32; c < s4 * 4; c += 32) {       // head (<4 cols)
            int p = pos[c];
            orow[c] = (p >= 0) ? bf2f(yr[p - n0]) : 0.0f;
        }
        for (int c4 = s4 + j32; c4 < e4; c4 += 32) {        // vector body
            i32x4 p = pos4[c4];
            f32x4 v;
            v.x = (p.x >= 0) ? bf2f(yr[p.x - n0]) : 0.0f;
            v.y = (p.y >= 0) ? bf2f(yr[p.y - n0]) : 0.0f;
            v.z = (p.z >= 0) ? bf2f(yr[p.z - n0]) : 0.0f;
            v.w = (p.w >= 0) ? bf2f(yr[p.w - n0]) : 0.0f;
            reinterpret_cast<f32x4*>(orow)[c4] = v;
        }
        for (int c = e4 * 4 + j32; c < hi; c += 32) {       // tail (<4 cols)
            int p = pos[c];
            orow[c] = (p >= 0) ? bf2f(yr[p - n0]) : 0.0f;
        }
    }
}

extern "C" void kernel_launch(void* const* d_in, const int* in_sizes, int n_in,
                              void* d_out, int out_size, void* d_ws, size_t ws_size,
                              hipStream_t stream) {
    const float* x      = (const float*)d_in[0];
    const float* W      = (const float*)d_in[1];
    const float* b      = (const float*)d_in[2];
    const int*   in_idx = (const int*)d_in[3];
    const int*   out_idx= (const int*)d_in[4];
    float* out = (float*)d_out;

    char* ws = (char*)d_ws;
    int* pos = (int*)ws;                                   // 16 KB
    u16* Wb  = (u16*)(ws + 16384);                         // 2 MB
    u16* Xa  = (u16*)(ws + 16384 + 2 * 1024 * 1024);       // 16 MB

    hipMemsetAsync(pos, 0xFF, OUT_F * sizeof(int), stream); // pos = -1
    prep_kernel<<<1024, 256, 0, stream>>>(W, out_idx, Wb, pos);
    gather_kernel<<<M_ROWS, 256, 0, stream>>>(x, in_idx, Xa);
    gemmfw_kernel<<<(M_ROWS / 128) * (AO / 128), 256, 0, stream>>>(
        Xa, Wb, b, out_idx, pos, out);
}

// Round 7
// 281.539 us; speedup vs baseline: 1.0178x; 1.0178x over previous
//
#include <hip/hip_runtime.h>
#include <hip/hip_bf16.h>

// NeuroselectiveLinear: y = gather(x, in_idx) @ W^T + b, scattered into a
// zeroed [B,S,4096] buffer.
// Pipeline: memset(pos) -> gather (fused: bf16 W + pos map for blocks<1024;
// coalesced x -> compact bf16 Xa) -> gemmfw (128x128 MFMA tiles, BK=32
// double-buffered, ~35 KB LDS -> 4 blocks/CU for cross-block phase overlap;
// epilogue writes each tile's DENSE out-column range with zeros merged --
// sorted out_idx makes ranges contiguous, disjoint, complete).

typedef unsigned short u16;
typedef u16   u16x4 __attribute__((ext_vector_type(4)));
typedef int   i32x4 __attribute__((ext_vector_type(4)));
typedef float f32x4 __attribute__((ext_vector_type(4)));
typedef __bf16 bf16x8 __attribute__((ext_vector_type(8)));

constexpr int IN_F  = 4096;
constexpr int OUT_F = 4096;
constexpr int AI    = 1024;      // ACTIVE_IN  (K)
constexpr int AO    = 1024;      // ACTIVE_OUT (N)
constexpr int M_ROWS = 4 * 2048; // 8192
constexpr int BK    = 32;        // K per LDS stage (32 k-tiles)
constexpr int NKT   = AI / BK;

__device__ __forceinline__ u16 f2bf(float f) {
    union { __hip_bfloat16 h; u16 u; } cv;
    cv.h = __float2bfloat16(f);   // RNE
    return cv.u;
}
__device__ __forceinline__ float bf2f(u16 u) {
    union { float f; unsigned int i; } cv;
    cv.i = ((unsigned int)u) << 16;
    return cv.f;
}

// One block per row: coalesced dense row load -> LDS, then LDS gather.
// Blocks 0..1023 additionally convert their W chunk to bf16 (Wb, row-major
// [AO][AI]) and scatter pos[out_idx[j]] = j (pos pre-memset to -1).
__global__ __launch_bounds__(256)
void gather_kernel(const float* __restrict__ x,
                   const int* __restrict__ in_idx,
                   const float* __restrict__ W,
                   const int* __restrict__ out_idx,
                   u16* __restrict__ Wb, int* __restrict__ pos,
                   u16* __restrict__ Xa) {
    __shared__ float xrow[IN_F];
    const int m = blockIdx.x;
    const int t = threadIdx.x;
    if (m < 1024) {             // fused prep: 1024*256 = 262144 f32x4 chunks
        const int t2 = m * 256 + t;
        if (t2 < AO) pos[out_idx[t2]] = t2;
        f32x4 w = reinterpret_cast<const f32x4*>(W)[t2];
        u16x4 wv;
        wv.x = f2bf(w.x); wv.y = f2bf(w.y); wv.z = f2bf(w.z); wv.w = f2bf(w.w);
        reinterpret_cast<u16x4*>(Wb)[t2] = wv;
    }
    const f32x4* src = reinterpret_cast<const f32x4*>(x + (size_t)m * IN_F);
#pragma unroll
    for (int i = 0; i < 4; ++i)
        *reinterpret_cast<f32x4*>(&xrow[i * 1024 + t * 4]) = src[i * 256 + t];
    __syncthreads();
    i32x4 idx = reinterpret_cast<const i32x4*>(in_idx)[t];
    u16x4 v;
    v.x = f2bf(xrow[idx.x]);
    v.y = f2bf(xrow[idx.y]);
    v.z = f2bf(xrow[idx.z]);
    v.w = f2bf(xrow[idx.w]);
    reinterpret_cast<u16x4*>(Xa + (size_t)m * AI)[t] = v;
}

// 128x128 tile, BK=32 dbuf, 4 waves (2x2), 4x4 16x16x32 frags/wave,
// global_load_lds w=16 staging. LDS ~34.8 KB (ys aliases A/B buffers)
// -> 4 blocks/CU so write phases overlap other blocks' GEMM phases.
__global__ __launch_bounds__(256, 4)
void gemmfw_kernel(const u16* __restrict__ Xa, const u16* __restrict__ Wb,
                   const float* __restrict__ bias,
                   const int* __restrict__ out_idx,
                   const int* __restrict__ pos, float* __restrict__ out) {
    __shared__ char L[128 * 136 * 2];          // 34816 B
    // A/B k-tiles: As[buf] at L+buf*8192, Bs[buf] at L+16384+buf*8192 (8 KB each)
    const int t    = threadIdx.x;
    const int wid  = t >> 6;
    const int lane = t & 63;
    const int n_lo = lane & 15;
    const int kg   = lane >> 4;
    // XCD swizzle: 512 blocks; each XCD gets 8 mb-groups x all 8 nb ->
    // its Xa panels (2MB) + full Wb (2MB) fit the 4MB per-XCD L2.
    const int orig = blockIdx.x;
    const int wgid = (orig & 7) * 64 + (orig >> 3);
    const int mb = wgid >> 3, nb = wgid & 7;
    const int m0 = mb * 128, n0 = nb * 128;
    const int wm = wid >> 1, wn = wid & 1;

    const int r16 = lane >> 2;        // 0..15 (row within 16-row strip)
    const int c8  = (lane & 3) * 8;   // col elem 0/8/16/24
    auto stage = [&](int buf, int k0) {
#pragma unroll
        for (int h = 0; h < 2; ++h) {
            const int row = h * 64 + wid * 16 + r16;
            const int db  = (h * 64 + wid * 16) * 64;   // dest byte base (row*64B)
            __builtin_amdgcn_global_load_lds(
                (const __attribute__((address_space(1))) void*)
                    (Xa + (size_t)(m0 + row) * AI + k0 + c8),
                (__attribute__((address_space(3))) void*)(L + buf * 8192 + db),
                16, 0, 0);
            __builtin_amdgcn_global_load_lds(
                (const __attribute__((address_space(1))) void*)
                    (Wb + (size_t)(n0 + row) * AI + k0 + c8),
                (__attribute__((address_space(3))) void*)(L + 16384 + buf * 8192 + db),
                16, 0, 0);
        }
    };

    f32x4 acc[4][4];
#pragma unroll
    for (int i = 0; i < 4; ++i)
#pragma unroll
        for (int j = 0; j < 4; ++j) acc[i][j] = (f32x4)0.0f;

    stage(0, 0);
    int buf = 0;
    for (int kt = 0; kt < NKT; ++kt) {
        __syncthreads();
        if (kt + 1 < NKT) stage(buf ^ 1, (kt + 1) * BK);
        bf16x8 a[4], b[4];
#pragma unroll
        for (int i = 0; i < 4; ++i)
            a[i] = *reinterpret_cast<const bf16x8*>(
                L + buf * 8192 + (wm * 64 + i * 16 + n_lo) * 64 + kg * 16);
#pragma unroll
        for (int j = 0; j < 4; ++j)
            b[j] = *reinterpret_cast<const bf16x8*>(
                L + 16384 + buf * 8192 + (wn * 64 + j * 16 + n_lo) * 64 + kg * 16);
#pragma unroll
        for (int i = 0; i < 4; ++i)
#pragma unroll
            for (int j = 0; j < 4; ++j)
                acc[i][j] = __builtin_amdgcn_mfma_f32_16x16x32_bf16(
                    a[i], b[j], acc[i][j], 0, 0, 0);
        buf ^= 1;
    }

    float bv[4];
#pragma unroll
    for (int j = 0; j < 4; ++j) bv[j] = bias[n0 + wn * 64 + j * 16 + n_lo];

    __syncthreads();  // all waves done with A/B tiles before aliasing as ys
    u16* ys = reinterpret_cast<u16*>(L);   // [128][136] bf16 = 34816 B
#pragma unroll
    for (int i = 0; i < 4; ++i)
#pragma unroll
        for (int j = 0; j < 4; ++j)
#pragma unroll
            for (int r = 0; r < 4; ++r)
                ys[(wm * 64 + i * 16 + kg * 4 + r) * 136 +
                   wn * 64 + j * 16 + n_lo] = f2bf(acc[i][j][r] + bv[j]);
    __syncthreads();

    // Dense write of this tile's out-column range (sorted out_idx =>
    // contiguous, disjoint, complete partition of [0,4096)).
    const int lo = (nb == 0) ? 0 : out_idx[nb * 128];
    const int hi = (nb == 7) ? OUT_F : out_idx[(nb + 1) * 128];
    const int s4 = (lo + 3) >> 2;     // first full f32x4
    const int e4 = hi >> 2;           // one past last full f32x4
    const i32x4* pos4 = reinterpret_cast<const i32x4*>(pos);
    const int rg = t >> 5, j32 = t & 31;  // 32 threads per row, 8 rows/iter
#pragma unroll 1
    for (int rr = 0; rr < 128; rr += 8) {
        const int row = rr + rg;
        float* orow = out + (size_t)(m0 + row) * OUT_F;
        const u16* yr = ys + row * 136;
        for (int c = lo + j32; c < s4 * 4; c += 32) {       // head (<4 cols)
            int p = pos[c];
            orow[c] = (p >= 0) ? bf2f(yr[p - n0]) : 0.0f;
        }
        for (int c4 = s4 + j32; c4 < e4; c4 += 32) {        // vector body
            i32x4 p = pos4[c4];
            f32x4 v;
            v.x = (p.x >= 0) ? bf2f(yr[p.x - n0]) : 0.0f;
            v.y = (p.y >= 0) ? bf2f(yr[p.y - n0]) : 0.0f;
            v.z = (p.z >= 0) ? bf2f(yr[p.z - n0]) : 0.0f;
            v.w = (p.w >= 0) ? bf2f(yr[p.w - n0]) : 0.0f;
            reinterpret_cast<f32x4*>(orow)[c4] = v;
        }
        for (int c = e4 * 4 + j32; c < hi; c += 32) {       // tail (<4 cols)
            int p = pos[c];
            orow[c] = (p >= 0) ? bf2f(yr[p - n0]) : 0.0f;
        }
    }
}

extern "C" void kernel_launch(void* const* d_in, const int* in_sizes, int n_in,
                              void* d_out, int out_size, void* d_ws, size_t ws_size,
                              hipStream_t stream) {
    const float* x      = (const float*)d_in[0];
    const float* W      = (const float*)d_in[1];
    const float* b      = (const float*)d_in[2];
    const int*   in_idx = (const int*)d_in[3];
    const int*   out_idx= (const int*)d_in[4];
    float* out = (float*)d_out;

    char* ws = (char*)d_ws;
    int* pos = (int*)ws;                                   // 16 KB
    u16* Wb  = (u16*)(ws + 16384);                         // 2 MB
    u16* Xa  = (u16*)(ws + 16384 + 2 * 1024 * 1024);       // 16 MB

    hipMemsetAsync(pos, 0xFF, OUT_F * sizeof(int), stream); // pos = -1
    gather_kernel<<<M_ROWS, 256, 0, stream>>>(x, in_idx, W, out_idx, Wb, pos, Xa);
    gemmfw_kernel<<<(M_ROWS / 128) * (AO / 128), 256, 0, stream>>>(
        Xa, Wb, b, out_idx, pos, out);
}